// Round 1
// baseline (1010.725 us; speedup 1.0000x reference)
//
#include <hip/hip_runtime.h>
#include <stdint.h>

// PressureLSTM: B=4096, T=512, F=32, H=32, gates=128 (i,f,g,o packing).
// One wave (64 threads) per 16 batch rows; sequential over T.
// Gate GEMMs via mfma_f32_16x16x32_bf16 with bf16x3 (hi/lo) split for ~fp32
// precision. C/D layout (col=lane&15, row=(lane>>4)*4+reg) makes the i/f/g/o
// for one (row, elem) lane-local -> elementwise LSTM update has no cross-lane
// traffic. h goes through LDS each step to re-form the MFMA A-fragment.

typedef __attribute__((ext_vector_type(8))) short short8;
typedef __attribute__((ext_vector_type(4))) float float4v;

#define T_LEN 512
#define B_ALL 4096

static __device__ __forceinline__ short f2bf(float f) {
    uint32_t u = __float_as_uint(f);
    uint32_t r = (u + 0x7FFFu + ((u >> 16) & 1u)) >> 16;
    return (short)(r & 0xFFFFu);
}
static __device__ __forceinline__ float bf2f(short s) {
    return __uint_as_float(((uint32_t)(uint16_t)s) << 16);
}
static __device__ __forceinline__ float sigf(float x) {
    return 1.0f / (1.0f + __expf(-x));
}
static __device__ __forceinline__ float tanhf_fast(float x) {
    // 1 - 2/(1+e^{2x}); correct limits at +-inf, no branches.
    return 1.0f - 2.0f / (1.0f + __expf(2.0f * x));
}

__global__ __launch_bounds__(64, 1) void lstm_fused_kernel(
    const float* __restrict__ x,     // [B, T, 32]
    const float* __restrict__ W_ih,  // [128, 32]
    const float* __restrict__ W_hh,  // [128, 32]
    const float* __restrict__ b_ih,  // [128]
    const float* __restrict__ b_hh,  // [128]
    const float* __restrict__ W_fc,  // [1, 32]
    const float* __restrict__ b_fc,  // [1]
    float* __restrict__ out)         // [B]
{
    const int lane = threadIdx.x;   // 0..63
    const int col  = lane & 15;
    const int q    = lane >> 4;     // 0..3 (k-block)
    const int k0   = q * 8;
    const int b0   = blockIdx.x * 16;

    __shared__ __align__(16) short lds_hi[16][32];
    __shared__ __align__(16) short lds_lo[16][32];
    __shared__ float hfin[16][32];

    // ---- Weight fragments (B operand: lane holds W[nt*16+col][k0..k0+7]) ----
    short8 wih_hi[8], wih_lo[8], whh_hi[8], whh_lo[8];
    float bias[8];
    #pragma unroll
    for (int nt = 0; nt < 8; ++nt) {
        const int g = nt * 16 + col;
        const float* wr = W_ih + g * 32 + k0;
        const float* hr = W_hh + g * 32 + k0;
        #pragma unroll
        for (int i = 0; i < 8; ++i) {
            float wv = wr[i];
            short whi = f2bf(wv);
            wih_hi[nt][i] = whi;
            wih_lo[nt][i] = f2bf(wv - bf2f(whi));
            float hv = hr[i];
            short hhi = f2bf(hv);
            whh_hi[nt][i] = hhi;
            whh_lo[nt][i] = f2bf(hv - bf2f(hhi));
        }
        bias[nt] = b_ih[g] + b_hh[g];
    }

    // ---- per-lane state: rows q*4+ri, elements col and col+16 ----
    float c0[4] = {0.f, 0.f, 0.f, 0.f};
    float c1[4] = {0.f, 0.f, 0.f, 0.f};
    float h0r[4] = {0.f, 0.f, 0.f, 0.f};
    float h1r[4] = {0.f, 0.f, 0.f, 0.f};
    short8 ah_hi = {0, 0, 0, 0, 0, 0, 0, 0};
    short8 ah_lo = {0, 0, 0, 0, 0, 0, 0, 0};

    // x A-fragment source: row b0+col, k-range [k0, k0+8)
    const float* xp = x + (size_t)(b0 + col) * (T_LEN * 32) + k0;
    float4v xa = *(const float4v*)(xp);
    float4v xb = *(const float4v*)(xp + 4);

    for (int t = 0; t < T_LEN; ++t) {
        // convert current x to bf16 hi/lo fragments
        short8 ax_hi, ax_lo;
        #pragma unroll
        for (int i = 0; i < 8; ++i) {
            float v = (i < 4) ? xa[i] : xb[i - 4];
            short hi_ = f2bf(v);
            ax_hi[i] = hi_;
            ax_lo[i] = f2bf(v - bf2f(hi_));
        }
        // prefetch next timestep's x (uniform branch)
        if (t + 1 < T_LEN) {
            const float* xn = xp + (size_t)(t + 1) * 32;
            xa = *(const float4v*)(xn);
            xb = *(const float4v*)(xn + 4);
        }

        // ---- gate GEMM: 8 N-tiles, bf16x3 split for x-proj and h-proj ----
        float4v acc[8];
        #pragma unroll
        for (int nt = 0; nt < 8; ++nt) {
            float4v a = {0.f, 0.f, 0.f, 0.f};
            a = __builtin_amdgcn_mfma_f32_16x16x32_bf16(ax_hi, wih_hi[nt], a, 0, 0, 0);
            a = __builtin_amdgcn_mfma_f32_16x16x32_bf16(ax_lo, wih_hi[nt], a, 0, 0, 0);
            a = __builtin_amdgcn_mfma_f32_16x16x32_bf16(ax_hi, wih_lo[nt], a, 0, 0, 0);
            a = __builtin_amdgcn_mfma_f32_16x16x32_bf16(ah_hi, whh_hi[nt], a, 0, 0, 0);
            a = __builtin_amdgcn_mfma_f32_16x16x32_bf16(ah_lo, whh_hi[nt], a, 0, 0, 0);
            a = __builtin_amdgcn_mfma_f32_16x16x32_bf16(ah_hi, whh_lo[nt], a, 0, 0, 0);
            acc[nt] = a;
        }

        // ---- elementwise LSTM update (all lane-local) + h -> LDS ----
        #pragma unroll
        for (int ri = 0; ri < 4; ++ri) {
            const int row = q * 4 + ri;
            // element j = col  (gate tiles 0,2,4,6)
            {
                float gi = sigf(acc[0][ri] + bias[0]);
                float gf = sigf(acc[2][ri] + bias[2]);
                float gg = tanhf_fast(acc[4][ri] + bias[4]);
                float go = sigf(acc[6][ri] + bias[6]);
                c0[ri] = gf * c0[ri] + gi * gg;
                float hv = go * tanhf_fast(c0[ri]);
                h0r[ri] = hv;
                short hi_ = f2bf(hv);
                lds_hi[row][col] = hi_;
                lds_lo[row][col] = f2bf(hv - bf2f(hi_));
            }
            // element j = col+16  (gate tiles 1,3,5,7)
            {
                float gi = sigf(acc[1][ri] + bias[1]);
                float gf = sigf(acc[3][ri] + bias[3]);
                float gg = tanhf_fast(acc[5][ri] + bias[5]);
                float go = sigf(acc[7][ri] + bias[7]);
                c1[ri] = gf * c1[ri] + gi * gg;
                float hv = go * tanhf_fast(c1[ri]);
                h1r[ri] = hv;
                short hi_ = f2bf(hv);
                lds_hi[row][col + 16] = hi_;
                lds_lo[row][col + 16] = f2bf(hv - bf2f(hi_));
            }
        }
        __syncthreads();
        // read back h as next A-fragment: row = col(lane&15), k = k0..k0+7
        ah_hi = *(const short8*)&lds_hi[col][k0];
        ah_lo = *(const short8*)&lds_lo[col][k0];
        __syncthreads();
    }

    // ---- epilogue: logits = h_last @ W_fc^T + b_fc ----
    #pragma unroll
    for (int ri = 0; ri < 4; ++ri) {
        hfin[q * 4 + ri][col]      = h0r[ri];
        hfin[q * 4 + ri][col + 16] = h1r[ri];
    }
    __syncthreads();
    if (lane < 16) {
        float s = b_fc[0];
        #pragma unroll
        for (int cc = 0; cc < 32; ++cc) s += hfin[lane][cc] * W_fc[cc];
        out[b0 + lane] = s;
    }
}

extern "C" void kernel_launch(void* const* d_in, const int* in_sizes, int n_in,
                              void* d_out, int out_size, void* d_ws, size_t ws_size,
                              hipStream_t stream) {
    const float* x    = (const float*)d_in[0];
    const float* W_ih = (const float*)d_in[1];
    const float* W_hh = (const float*)d_in[2];
    const float* b_ih = (const float*)d_in[3];
    const float* b_hh = (const float*)d_in[4];
    const float* W_fc = (const float*)d_in[5];
    const float* b_fc = (const float*)d_in[6];
    float* out = (float*)d_out;

    lstm_fused_kernel<<<dim3(B_ALL / 16), dim3(64), 0, stream>>>(
        x, W_ih, W_hh, b_ih, b_hh, W_fc, b_fc, out);
}

// Round 2
// 474.592 us; speedup vs baseline: 2.1297x; 2.1297x over previous
//
#include <hip/hip_runtime.h>
#include <stdint.h>

// PressureLSTM: B=4096, T=512, F=32, H=32, gates=128 (i,f,g,o).
// 2 waves per 16-row batch tile (N-split of gate tiles): wave w owns gate
// tiles {w, w+2, w+4, w+6} == all 4 gate types for output elements col+16w.
// Gate GEMMs via mfma_f32_16x16x32_bf16 with bf16x3 (hi/lo) split.
// Fast activations via v_exp_f32/v_rcp_f32. x-projection pipelined off the
// h critical path; single barrier/step via LDS double buffer.

typedef __attribute__((ext_vector_type(8))) short short8;
typedef __attribute__((ext_vector_type(4))) float float4v;

#define T_LEN 512
#define B_ALL 4096
#define LDS_PITCH 40  // shorts; 80 B row stride: 16B-aligned b128, spreads banks

static __device__ __forceinline__ void split_bf(float v, short* hi, short* lo) {
    // hi = truncated-bf16(v) (exact masked f32), lo = trunc-bf16(v - hi).
    uint32_t u = __float_as_uint(v);
    uint32_t uh = u & 0xFFFF0000u;
    float lof = v - __uint_as_float(uh);
    *hi = (short)(uh >> 16);
    *lo = (short)(__float_as_uint(lof) >> 16);
}
static __device__ __forceinline__ float bf2f(short s) {
    return __uint_as_float(((uint32_t)(uint16_t)s) << 16);
}
static __device__ __forceinline__ float sigf(float x) {
    // 1/(1+exp(-x)) ; exp(-x) = 2^(-x*log2e). Saturates correctly at +-inf.
    float e = __builtin_amdgcn_exp2f(x * -1.44269504f);
    return __builtin_amdgcn_rcpf(1.0f + e);
}
static __device__ __forceinline__ float tanh_fast(float x) {
    // 1 - 2/(1+exp(2x)) ; exp(2x) = 2^(x*2*log2e).
    float e = __builtin_amdgcn_exp2f(x * 2.88539008f);
    return 1.0f - 2.0f * __builtin_amdgcn_rcpf(1.0f + e);
}

__global__ __launch_bounds__(128, 1) void lstm_fused_kernel(
    const float* __restrict__ x,     // [B, T, 32]
    const float* __restrict__ W_ih,  // [128, 32]
    const float* __restrict__ W_hh,  // [128, 32]
    const float* __restrict__ b_ih,  // [128]
    const float* __restrict__ b_hh,  // [128]
    const float* __restrict__ W_fc,  // [1, 32]
    const float* __restrict__ b_fc,  // [1]
    float* __restrict__ out)         // [B]
{
    const int tid  = threadIdx.x;    // 0..127
    const int wv   = tid >> 6;       // wave 0/1
    const int lane = tid & 63;
    const int col  = lane & 15;
    const int q    = lane >> 4;      // 0..3 (k-block / row-group)
    const int k0   = q * 8;
    const int b0   = blockIdx.x * 16;
    const int jcol = col + 16 * wv;  // h element column this wave owns

    __shared__ __align__(16) short lds_hi[2][16][LDS_PITCH];
    __shared__ __align__(16) short lds_lo[2][16][LDS_PITCH];

    // ---- weight fragments: tile tt -> gate type tt, gate row g=(2tt+wv)*16+col
    short8 wih_hi[4], wih_lo[4], whh_hi[4], whh_lo[4];
    float bias[4];
    #pragma unroll
    for (int tt = 0; tt < 4; ++tt) {
        const int g = (tt * 2 + wv) * 16 + col;
        const float* wr = W_ih + g * 32 + k0;
        const float* hr = W_hh + g * 32 + k0;
        #pragma unroll
        for (int i = 0; i < 8; ++i) {
            short hi_, lo_;
            split_bf(wr[i], &hi_, &lo_);
            wih_hi[tt][i] = hi_; wih_lo[tt][i] = lo_;
            split_bf(hr[i], &hi_, &lo_);
            whh_hi[tt][i] = hi_; whh_lo[tt][i] = lo_;
        }
        bias[tt] = b_ih[g] + b_hh[g];
    }

    float c[4] = {0.f, 0.f, 0.f, 0.f};
    short8 ah_hi = {0,0,0,0,0,0,0,0};
    short8 ah_lo = {0,0,0,0,0,0,0,0};

    const float* xrow = x + (size_t)(b0 + col) * (T_LEN * 32);

    // ---- prologue: xacc = bias + x-projection for t=0
    float4v xacc[4];
    {
        float4v xa = *(const float4v*)(xrow + k0);
        float4v xb = *(const float4v*)(xrow + k0 + 4);
        short8 ax_hi, ax_lo;
        #pragma unroll
        for (int i = 0; i < 8; ++i) {
            float v = (i < 4) ? xa[i] : xb[i - 4];
            short hi_, lo_;
            split_bf(v, &hi_, &lo_);
            ax_hi[i] = hi_; ax_lo[i] = lo_;
        }
        #pragma unroll
        for (int tt = 0; tt < 4; ++tt) {
            float4v a = {bias[tt], bias[tt], bias[tt], bias[tt]};
            a = __builtin_amdgcn_mfma_f32_16x16x32_bf16(ax_hi, wih_hi[tt], a, 0, 0, 0);
            a = __builtin_amdgcn_mfma_f32_16x16x32_bf16(ax_lo, wih_hi[tt], a, 0, 0, 0);
            a = __builtin_amdgcn_mfma_f32_16x16x32_bf16(ax_hi, wih_lo[tt], a, 0, 0, 0);
            xacc[tt] = a;
        }
    }

    for (int t = 0; t < T_LEN; ++t) {
        // issue next x load early (independent of h chain)
        float4v xa, xb;
        const bool more = (t + 1 < T_LEN);
        if (more) {
            const float* xn = xrow + (size_t)(t + 1) * 32 + k0;
            xa = *(const float4v*)(xn);
            xb = *(const float4v*)(xn + 4);
        }

        // ---- h-projection for this step (critical path): 3 MFMAs/tile
        float4v acc[4];
        #pragma unroll
        for (int tt = 0; tt < 4; ++tt) {
            float4v a = xacc[tt];
            a = __builtin_amdgcn_mfma_f32_16x16x32_bf16(ah_hi, whh_hi[tt], a, 0, 0, 0);
            a = __builtin_amdgcn_mfma_f32_16x16x32_bf16(ah_lo, whh_hi[tt], a, 0, 0, 0);
            a = __builtin_amdgcn_mfma_f32_16x16x32_bf16(ah_hi, whh_lo[tt], a, 0, 0, 0);
            acc[tt] = a;
        }

        // ---- elementwise update: rows q*4+ri, element jcol
        #pragma unroll
        for (int ri = 0; ri < 4; ++ri) {
            float gi = sigf(acc[0][ri]);
            float gf = sigf(acc[1][ri]);
            float gg = tanh_fast(acc[2][ri]);
            float go = sigf(acc[3][ri]);
            float cn = gf * c[ri] + gi * gg;
            c[ri] = cn;
            float hv = go * tanh_fast(cn);
            short hi_, lo_;
            split_bf(hv, &hi_, &lo_);
            lds_hi[t & 1][q * 4 + ri][jcol] = hi_;
            lds_lo[t & 1][q * 4 + ri][jcol] = lo_;
        }

        // ---- next step's x-projection (off critical path)
        if (more) {
            short8 ax_hi, ax_lo;
            #pragma unroll
            for (int i = 0; i < 8; ++i) {
                float v = (i < 4) ? xa[i] : xb[i - 4];
                short hi_, lo_;
                split_bf(v, &hi_, &lo_);
                ax_hi[i] = hi_; ax_lo[i] = lo_;
            }
            #pragma unroll
            for (int tt = 0; tt < 4; ++tt) {
                float4v a = {bias[tt], bias[tt], bias[tt], bias[tt]};
                a = __builtin_amdgcn_mfma_f32_16x16x32_bf16(ax_hi, wih_hi[tt], a, 0, 0, 0);
                a = __builtin_amdgcn_mfma_f32_16x16x32_bf16(ax_lo, wih_hi[tt], a, 0, 0, 0);
                a = __builtin_amdgcn_mfma_f32_16x16x32_bf16(ax_hi, wih_lo[tt], a, 0, 0, 0);
                xacc[tt] = a;
            }
        }

        __syncthreads();
        // A-fragment for next step: h[row=col][k0..k0+7]
        ah_hi = *(const short8*)&lds_hi[t & 1][col][k0];
        ah_lo = *(const short8*)&lds_lo[t & 1][col][k0];
    }

    // ---- epilogue: logits = h_last @ W_fc^T + b_fc ; final h is in buf 1
    if (tid < 16) {
        float s = b_fc[0];
        #pragma unroll
        for (int cc = 0; cc < 32; ++cc) {
            float hv = bf2f(lds_hi[1][tid][cc]) + bf2f(lds_lo[1][tid][cc]);
            s += hv * W_fc[cc];
        }
        out[b0 + tid] = s;
    }
}

extern "C" void kernel_launch(void* const* d_in, const int* in_sizes, int n_in,
                              void* d_out, int out_size, void* d_ws, size_t ws_size,
                              hipStream_t stream) {
    const float* x    = (const float*)d_in[0];
    const float* W_ih = (const float*)d_in[1];
    const float* W_hh = (const float*)d_in[2];
    const float* b_ih = (const float*)d_in[3];
    const float* b_hh = (const float*)d_in[4];
    const float* W_fc = (const float*)d_in[5];
    const float* b_fc = (const float*)d_in[6];
    float* out = (float*)d_out;

    lstm_fused_kernel<<<dim3(B_ALL / 16), dim3(128), 0, stream>>>(
        x, W_ih, W_hh, b_ih, b_hh, W_fc, b_fc, out);
}

// Round 3
// 449.188 us; speedup vs baseline: 2.2501x; 1.0566x over previous
//
#include <hip/hip_runtime.h>
#include <stdint.h>

// PressureLSTM: B=4096, T=512, F=32, H=32, gates=128 (i,f,g,o).
// 8 waves per 16-row batch tile: wave w owns gate tile w (gates 16w..16w+15).
// Per step: each wave does 3 critical h-proj MFMAs (bf16x3 split) + 3 off-path
// x-proj MFMAs for t+1; gate pre-acts exchanged through LDS in fp32; the 512
// threads then each update exactly ONE h element (5 activations). Two barriers
// per step; h double-buffered in LDS as bf16 hi/lo A-fragments.

typedef __attribute__((ext_vector_type(8))) short short8;
typedef __attribute__((ext_vector_type(4))) float float4v;

#define T_LEN 512
#define B_ALL 4096
#define GPITCH 20  // floats per gacc row: 80 B => b128-aligned writes, spreads banks
#define HPITCH 40  // shorts per h row: 80 B

static __device__ __forceinline__ void split_bf(float v, short* hi, short* lo) {
    // hi = truncated-bf16(v) (exact masked f32), lo = trunc-bf16(v - hi).
    uint32_t u = __float_as_uint(v);
    uint32_t uh = u & 0xFFFF0000u;
    float lof = v - __uint_as_float(uh);
    *hi = (short)(uh >> 16);
    *lo = (short)(__float_as_uint(lof) >> 16);
}
static __device__ __forceinline__ float bf2f(short s) {
    return __uint_as_float(((uint32_t)(uint16_t)s) << 16);
}
static __device__ __forceinline__ float sigf(float x) {
    float e = __builtin_amdgcn_exp2f(x * -1.44269504f);
    return __builtin_amdgcn_rcpf(1.0f + e);
}
static __device__ __forceinline__ float tanh_fast(float x) {
    float e = __builtin_amdgcn_exp2f(x * 2.88539008f);
    return 1.0f - 2.0f * __builtin_amdgcn_rcpf(1.0f + e);
}

__global__ __launch_bounds__(512, 1) void lstm_fused_kernel(
    const float* __restrict__ x,     // [B, T, 32]
    const float* __restrict__ W_ih,  // [128, 32]
    const float* __restrict__ W_hh,  // [128, 32]
    const float* __restrict__ b_ih,  // [128]
    const float* __restrict__ b_hh,  // [128]
    const float* __restrict__ W_fc,  // [1, 32]
    const float* __restrict__ b_fc,  // [1]
    float* __restrict__ out)         // [B]
{
    const int tid  = threadIdx.x;    // 0..511
    const int wv   = tid >> 6;       // wave = gate tile 0..7
    const int lane = tid & 63;
    const int col  = lane & 15;      // MFMA col (gate within tile / batch row for A)
    const int q    = lane >> 4;      // 0..3
    const int k0   = q * 8;
    const int b0   = blockIdx.x * 16;
    const int er   = tid & 15;       // elementwise: batch row
    const int ee   = tid >> 4;       // elementwise: h element 0..31

    __shared__ __align__(16) float gacc[128][GPITCH];
    __shared__ __align__(16) short lds_hi[2][16][HPITCH];
    __shared__ __align__(16) short lds_lo[2][16][HPITCH];

    // ---- weight fragment for tile wv: gate row g = wv*16+col, k = k0..k0+7
    short8 wih_hi, wih_lo, whh_hi, whh_lo;
    float bias;
    {
        const int g = wv * 16 + col;
        const float* wr = W_ih + g * 32 + k0;
        const float* hr = W_hh + g * 32 + k0;
        #pragma unroll
        for (int i = 0; i < 8; ++i) {
            short hi_, lo_;
            split_bf(wr[i], &hi_, &lo_);
            wih_hi[i] = hi_; wih_lo[i] = lo_;
            split_bf(hr[i], &hi_, &lo_);
            whh_hi[i] = hi_; whh_lo[i] = lo_;
        }
        bias = b_ih[g] + b_hh[g];
    }

    float c = 0.f;  // this thread's cell state for (er, ee)
    short8 ah_hi = {0,0,0,0,0,0,0,0};
    short8 ah_lo = {0,0,0,0,0,0,0,0};

    const float* xrow = x + (size_t)(b0 + col) * (T_LEN * 32) + k0;

    // ---- prologue: xacc = bias + x-projection for t=0 (tile wv)
    float4v xacc;
    {
        float4v xa = *(const float4v*)(xrow);
        float4v xb = *(const float4v*)(xrow + 4);
        short8 ax_hi, ax_lo;
        #pragma unroll
        for (int i = 0; i < 8; ++i) {
            float v = (i < 4) ? xa[i] : xb[i - 4];
            short hi_, lo_;
            split_bf(v, &hi_, &lo_);
            ax_hi[i] = hi_; ax_lo[i] = lo_;
        }
        float4v a = {bias, bias, bias, bias};
        a = __builtin_amdgcn_mfma_f32_16x16x32_bf16(ax_hi, wih_hi, a, 0, 0, 0);
        a = __builtin_amdgcn_mfma_f32_16x16x32_bf16(ax_lo, wih_hi, a, 0, 0, 0);
        a = __builtin_amdgcn_mfma_f32_16x16x32_bf16(ax_hi, wih_lo, a, 0, 0, 0);
        xacc = a;
    }

    for (int t = 0; t < T_LEN; ++t) {
        // ---- h-projection for tile wv (critical path): 3 MFMAs
        float4v acc = xacc;
        acc = __builtin_amdgcn_mfma_f32_16x16x32_bf16(ah_hi, whh_hi, acc, 0, 0, 0);
        acc = __builtin_amdgcn_mfma_f32_16x16x32_bf16(ah_lo, whh_hi, acc, 0, 0, 0);
        acc = __builtin_amdgcn_mfma_f32_16x16x32_bf16(ah_hi, whh_lo, acc, 0, 0, 0);
        // gate pre-acts -> LDS (fp32): rows q*4..q*4+3 of gate wv*16+col
        *(float4v*)&gacc[wv * 16 + col][q * 4] = acc;

        // ---- next step's x-projection (off critical path)
        const bool more = (t + 1 < T_LEN);
        if (more) {
            const float* xn = xrow + (size_t)(t + 1) * 32;
            float4v xa = *(const float4v*)(xn);
            float4v xb = *(const float4v*)(xn + 4);
            short8 ax_hi, ax_lo;
            #pragma unroll
            for (int i = 0; i < 8; ++i) {
                float v = (i < 4) ? xa[i] : xb[i - 4];
                short hi_, lo_;
                split_bf(v, &hi_, &lo_);
                ax_hi[i] = hi_; ax_lo[i] = lo_;
            }
            float4v a = {bias, bias, bias, bias};
            a = __builtin_amdgcn_mfma_f32_16x16x32_bf16(ax_hi, wih_hi, a, 0, 0, 0);
            a = __builtin_amdgcn_mfma_f32_16x16x32_bf16(ax_lo, wih_hi, a, 0, 0, 0);
            a = __builtin_amdgcn_mfma_f32_16x16x32_bf16(ax_hi, wih_lo, a, 0, 0, 0);
            xacc = a;
        }

        __syncthreads();  // gates visible

        // ---- elementwise: this thread owns (row er, element ee)
        {
            float gi = sigf(gacc[0 * 32 + ee][er]);
            float gf = sigf(gacc[1 * 32 + ee][er]);
            float gg = tanh_fast(gacc[2 * 32 + ee][er]);
            float go = sigf(gacc[3 * 32 + ee][er]);
            float cn = gf * c + gi * gg;
            c = cn;
            float hv = go * tanh_fast(cn);
            short hi_, lo_;
            split_bf(hv, &hi_, &lo_);
            lds_hi[t & 1][er][ee] = hi_;
            lds_lo[t & 1][er][ee] = lo_;
        }

        __syncthreads();  // h visible

        // A-fragment for next step: h[row=col][k0..k0+7]
        ah_hi = *(const short8*)&lds_hi[t & 1][col][k0];
        ah_lo = *(const short8*)&lds_lo[t & 1][col][k0];
    }

    // ---- epilogue: logits = h_last @ W_fc^T + b_fc ; final h is in buf 1
    if (tid < 16) {
        float s = b_fc[0];
        #pragma unroll
        for (int cc = 0; cc < 32; ++cc) {
            float hv = bf2f(lds_hi[1][tid][cc]) + bf2f(lds_lo[1][tid][cc]);
            s += hv * W_fc[cc];
        }
        out[b0 + tid] = s;
    }
}

extern "C" void kernel_launch(void* const* d_in, const int* in_sizes, int n_in,
                              void* d_out, int out_size, void* d_ws, size_t ws_size,
                              hipStream_t stream) {
    const float* x    = (const float*)d_in[0];
    const float* W_ih = (const float*)d_in[1];
    const float* W_hh = (const float*)d_in[2];
    const float* b_ih = (const float*)d_in[3];
    const float* b_hh = (const float*)d_in[4];
    const float* W_fc = (const float*)d_in[5];
    const float* b_fc = (const float*)d_in[6];
    float* out = (float*)d_out;

    lstm_fused_kernel<<<dim3(B_ALL / 16), dim3(512), 0, stream>>>(
        x, W_ih, W_hh, b_ih, b_hh, W_fc, b_fc, out);
}